// Round 14
// baseline (259.527 us; speedup 1.0000x reference)
//
#include <hip/hip_runtime.h>
#include <hip/hip_bf16.h>

using floatx4 = __attribute__((ext_vector_type(4))) float;
using shortx8 = __attribute__((ext_vector_type(8))) short;
using uintx2  = __attribute__((ext_vector_type(2))) unsigned int;

constexpr int M = 32, N = 4096, K = 4096;
constexpr int WAVES = 8;              // waves per block
constexpr int WSPAN = K / WAVES;      // 512 k per wave
constexpr int CH = 64;                // k per chunk
constexpr int NCH = WSPAN / CH;       // 8 chunks per wave

__device__ __forceinline__ unsigned int pk_bf16(float a, float b) {
    __hip_bfloat16 ha = __float2bfloat16(a), hb = __float2bfloat16(b);
    return (unsigned int)*reinterpret_cast<unsigned short*>(&ha) |
           ((unsigned int)*reinterpret_cast<unsigned short*>(&hb) << 16);
}

// ---- init: pack x into fragment-ordered bf16 (R8/R12 proven path)
__global__ __launch_bounds__(256) void pack_x(
    const float* __restrict__ x, short* __restrict__ xfrag)
{
    int g = blockIdx.x * blockDim.x + threadIdx.x;   // 16384 threads
    int kblk = g >> 7, rem = g & 127;
    int half = rem >> 6, lane = rem & 63;
    int b = half * 16 + (lane & 15);
    int k = kblk * 32 + (lane >> 4) * 8;
    const float* src = x + (size_t)b * K + k;
    shortx8 v;
    #pragma unroll
    for (int j = 0; j < 8; ++j) {
        __hip_bfloat16 h = __float2bfloat16(src[j]);
        v[j] = *reinterpret_cast<short*>(&h);
    }
    *reinterpret_cast<shortx8*>(xfrag + (size_t)g * 8) = v;
}

// ---- main GEMM: R12 (best known), unchanged.
__global__ __launch_bounds__(512, 4) void gemm_main(
    const float* __restrict__ W, const float* __restrict__ scales,
    const short* __restrict__ xfrag, const float* __restrict__ tscale,
    const float* __restrict__ bias, float* __restrict__ out)
{
    __shared__ __align__(16) char lds[WAVES * 2 * 2048];   // 32 KB

    const int t    = threadIdx.x;
    const int lane = t & 63;
    const int wave = t >> 6;
    const int o0   = blockIdx.x * 16;
    const int kw0  = wave * WSPAN;
    const int rot  = blockIdx.x & (NCH - 1);

    const float rt = 1.0f / tscale[0];

    floatx4 wr[2][4]; float sc[2][4];
    shortx8 xa[2][2], xb[2][2];

    auto issueW = [&](int c, int sl) {
        const int cm = (c + rot) & (NCH - 1);
        const int kc = kw0 + cm * CH;
        #pragma unroll
        for (int j = 0; j < 4; ++j) {
            int flat = j * 64 + lane, row = flat >> 4, seg = flat & 15;
            wr[sl][j] = *reinterpret_cast<const floatx4*>(
                W + (size_t)(o0 + row) * K + kc + seg * 4);
            sc[sl][j] = scales[(size_t)(o0 + row) * (K / 16) + (kc >> 4) + (seg >> 2)];
        }
        __builtin_amdgcn_sched_barrier(0);
    };
    auto loadX = [&](int c, int sl) {
        const int cm = (c + rot) & (NCH - 1);
        const int kb0 = (kw0 + cm * CH) >> 5;
        #pragma unroll
        for (int b = 0; b < 2; ++b) {
            xa[sl][b] = *reinterpret_cast<const shortx8*>(
                xfrag + ((size_t)(kb0 + b) * 2 + 0) * 512 + lane * 8);
            xb[sl][b] = *reinterpret_cast<const shortx8*>(
                xfrag + ((size_t)(kb0 + b) * 2 + 1) * 512 + lane * 8);
        }
        __builtin_amdgcn_sched_barrier(0);
    };

    char* mybuf = lds + wave * 4096;
    auto stage = [&](int c, int sl) {
        char* buf = mybuf + sl * 2048;
        #pragma unroll
        for (int j = 0; j < 4; ++j) {
            int flat = j * 64 + lane, row = flat >> 4, seg = flat & 15;
            float rs = rt * __builtin_amdgcn_rcpf(sc[sl][j]);
            uintx2 pv = { pk_bf16(wr[sl][j][0] * rs, wr[sl][j][1] * rs),
                          pk_bf16(wr[sl][j][2] * rs, wr[sl][j][3] * rs) };
            int slot = seg >> 1, half = seg & 1;
            *reinterpret_cast<uintx2*>(
                buf + row * 128 + ((slot ^ row) & 7) * 16 + half * 8) = pv;
        }
    };

    floatx4 acc0 = {0.f, 0.f, 0.f, 0.f};
    floatx4 acc1 = {0.f, 0.f, 0.f, 0.f};
    const int fr = lane & 15, kg = lane >> 4;

    issueW(0, 0);
    issueW(1, 1);
    loadX(0, 0);

    #pragma unroll
    for (int c = 0; c < NCH; ++c) {
        const int sl = c & 1;
        if (c + 1 < NCH) loadX(c + 1, sl ^ 1);
        stage(c, sl);
        if (c + 2 < NCH) issueW(c + 2, sl);
        char* buf = mybuf + sl * 2048;
        #pragma unroll
        for (int b = 0; b < 2; ++b) {
            int slot = b * 4 + kg;
            shortx8 wf = *reinterpret_cast<const shortx8*>(
                buf + fr * 128 + ((slot ^ fr) & 7) * 16);
            acc0 = __builtin_amdgcn_mfma_f32_16x16x32_bf16(xa[sl][b], wf, acc0, 0, 0, 0);
            acc1 = __builtin_amdgcn_mfma_f32_16x16x32_bf16(xb[sl][b], wf, acc1, 0, 0, 0);
        }
    }

    __syncthreads();
    float* red = (float*)lds;
    #pragma unroll
    for (int r = 0; r < 4; ++r) {
        red[(wave * 8 + r) * 64 + lane]     = acc0[r];
        red[(wave * 8 + 4 + r) * 64 + lane] = acc1[r];
    }
    __syncthreads();
    {
        int b = t >> 4, oc = t & 15;
        int hi = b >> 4, kgq = (b >> 2) & 3, r = b & 3;
        int e = hi * 4 + r, ls = kgq * 16 + oc;
        float v = bias[o0 + oc];
        #pragma unroll
        for (int w = 0; w < WAVES; ++w)
            v += red[(w * 8 + e) * 64 + ls];
        out[(size_t)b * N + o0 + oc] = v;
    }
}

// ================= DIAGNOSTIC PROBES (this round only) =================
// All read the 256MB workspace (L3-defeating), long enough to rank in top-5.
// Sinks written back into d_ws (scratch; values never used for output).

// Probe A: linear stream, gemm's grid shape (256 blk x 512 thr), 2 passes.
__global__ __launch_bounds__(512) void probe_lin_g(
    const floatx4* __restrict__ src, float* __restrict__ sink)
{
    const size_t NT = 256 * 512;
    const size_t N4 = (size_t)16 * 1024 * 1024;   // 256MB / 16B
    size_t base = blockIdx.x * 512 + threadIdx.x;
    floatx4 a0 = {0,0,0,0}, a1 = {0,0,0,0}, a2 = {0,0,0,0}, a3 = {0,0,0,0};
    for (int p = 0; p < 2; ++p)
        for (size_t i = base; i + 3 * NT < N4; i += 4 * NT) {
            a0 += src[i]; a1 += src[i + NT]; a2 += src[i + 2 * NT]; a3 += src[i + 3 * NT];
        }
    floatx4 s = a0 + a1 + a2 + a3;
    sink[base] = s[0] + s[1] + s[2] + s[3];
}

// Probe B: exact gemm W addressing (4 rows x 256B per instr, 16KB row stride),
// 256 blk x 512 thr, 4 sheets of 64MB, 2 passes.
__global__ __launch_bounds__(512) void probe_wpat(
    const float* __restrict__ src, float* __restrict__ sink)
{
    const int t = threadIdx.x, lane = t & 63, wave = t >> 6;
    const int bx = blockIdx.x;
    floatx4 acc = {0,0,0,0};
    for (int p = 0; p < 2; ++p)
        for (int s = 0; s < 4; ++s) {
            const float* sheet = src + (size_t)s * 4096 * 4096;
            const int kw0 = wave * 512;
            for (int c = 0; c < NCH; ++c) {
                const int kc = kw0 + c * 64;
                #pragma unroll
                for (int j = 0; j < 4; ++j) {
                    int flat = j * 64 + lane, row = flat >> 4, seg = flat & 15;
                    acc += *reinterpret_cast<const floatx4*>(
                        sheet + (size_t)(bx * 16 + row) * 4096 + kc + seg * 4);
                }
            }
        }
    sink[blockIdx.x * 512 + t] = acc[0] + acc[1] + acc[2] + acc[3];
}

// Probe C: linear stream, saturation grid (2048 blk x 256 thr), 2 passes.
__global__ __launch_bounds__(256) void probe_lin_big(
    const floatx4* __restrict__ src, float* __restrict__ sink)
{
    const size_t NT = 2048 * 256;
    const size_t N4 = (size_t)16 * 1024 * 1024;
    size_t base = blockIdx.x * 256 + threadIdx.x;
    floatx4 a0 = {0,0,0,0}, a1 = {0,0,0,0};
    for (int p = 0; p < 2; ++p)
        for (size_t i = base; i + NT < N4; i += 2 * NT) {
            a0 += src[i]; a1 += src[i + NT];
        }
    floatx4 s = a0 + a1;
    sink[base] = s[0] + s[1] + s[2] + s[3];
}

// ---- fallback (tiny ws): atomic split-K, x as f32
__global__ __launch_bounds__(256) void init_bias(
    const float* __restrict__ bias, float* __restrict__ out)
{
    int i = blockIdx.x * blockDim.x + threadIdx.x;
    if (i < M * N) out[i] = bias[i & (N - 1)];
}

__global__ __launch_bounds__(256) void gemm_atomic(
    const float* __restrict__ W, const float* __restrict__ scales,
    const float* __restrict__ xf32, const float* __restrict__ tscale,
    float* __restrict__ out)
{
    const int lane = threadIdx.x & 63;
    const int wave = threadIdx.x >> 6;
    const int o0 = blockIdx.x * 64 + wave * 16;
    const int k0 = blockIdx.y * 128;
    const int row = lane & 15, kg = lane >> 4;

    const float* wp  = W + (size_t)(o0 + row) * K + k0 + kg * 8;
    const float* sp  = scales + (size_t)(o0 + row) * (K / 16) + (k0 >> 4) + (kg >> 1);
    const float* xf0 = xf32 + (size_t)row * K + k0 + kg * 8;
    const float* xf1 = xf32 + (size_t)(row + 16) * K + k0 + kg * 8;
    const float rt = 1.0f / tscale[0];

    floatx4 acc0 = {0.f, 0.f, 0.f, 0.f};
    floatx4 acc1 = {0.f, 0.f, 0.f, 0.f};
    for (int i = 0; i < 4; ++i) {
        floatx4 w0 = *reinterpret_cast<const floatx4*>(wp + i * 32);
        floatx4 w1 = *reinterpret_cast<const floatx4*>(wp + i * 32 + 4);
        float s = sp[2 * i];
        shortx8 xav, xbv, wf;
        const float rs = rt / s;
        #pragma unroll
        for (int j = 0; j < 8; ++j) {
            float a = xf0[i * 32 + j], bb = xf1[i * 32 + j];
            float wv = (j < 4 ? w0[j] : w1[j - 4]) * rs;
            __hip_bfloat16 ha = __float2bfloat16(a);
            __hip_bfloat16 hb = __float2bfloat16(bb);
            __hip_bfloat16 hw = __float2bfloat16(wv);
            xav[j] = *reinterpret_cast<short*>(&ha);
            xbv[j] = *reinterpret_cast<short*>(&hb);
            wf[j]  = *reinterpret_cast<short*>(&hw);
        }
        acc0 = __builtin_amdgcn_mfma_f32_16x16x32_bf16(xav, wf, acc0, 0, 0, 0);
        acc1 = __builtin_amdgcn_mfma_f32_16x16x32_bf16(xbv, wf, acc1, 0, 0, 0);
    }
    float* op0 = out + (size_t)(kg * 4) * N + o0 + row;
    float* op1 = out + (size_t)(16 + kg * 4) * N + o0 + row;
    #pragma unroll
    for (int r = 0; r < 4; ++r) {
        atomicAdd(op0 + (size_t)r * N, acc0[r]);
        atomicAdd(op1 + (size_t)r * N, acc1[r]);
    }
}

extern "C" void kernel_launch(void* const* d_in, const int* in_sizes, int n_in,
                              void* d_out, int out_size, void* d_ws, size_t ws_size,
                              hipStream_t stream)
{
    const float* x      = (const float*)d_in[0];
    const float* W      = (const float*)d_in[1];
    const float* tscale = (const float*)d_in[2];
    const float* scales = (const float*)d_in[3];
    const float* bias   = (const float*)d_in[4];
    float* out = (float*)d_out;

    const size_t xfrag_bytes = (size_t)M * K * sizeof(short);   // 256 KiB

    if (ws_size >= xfrag_bytes) {
        short* xfrag = (short*)d_ws;
        pack_x<<<(M * K / 8 + 255) / 256, 256, 0, stream>>>(x, xfrag);
        gemm_main<<<N / 16, 512, 0, stream>>>(W, scales, xfrag, tscale, bias, out);

        // ---- diagnostic probes (only if the full 256MB scratch exists) ----
        if (ws_size >= (size_t)256 * 1024 * 1024) {
            const floatx4* ws4 = (const floatx4*)d_ws;
            const float*   wsf = (const float*)d_ws;
            float* sink = (float*)d_ws;   // scratch sink; values unused
            probe_lin_g  <<<256, 512, 0, stream>>>(ws4, sink);
            probe_wpat   <<<256, 512, 0, stream>>>(wsf, sink);
            probe_lin_big<<<2048, 256, 0, stream>>>(ws4, sink);
        }
    } else {
        init_bias<<<(M * N + 255) / 256, 256, 0, stream>>>(bias, out);
        dim3 grid(N / 64, K / 128);
        gemm_atomic<<<grid, 256, 0, stream>>>(W, scales, x, tscale, out);
    }
}

// Round 15
// 24.831 us; speedup vs baseline: 10.4516x; 10.4516x over previous
//
#include <hip/hip_runtime.h>
#include <hip/hip_bf16.h>

using floatx4 = __attribute__((ext_vector_type(4))) float;
using shortx8 = __attribute__((ext_vector_type(8))) short;
using uintx2  = __attribute__((ext_vector_type(2))) unsigned int;

constexpr int M = 32, N = 4096, K = 4096;
constexpr int WAVES = 16;             // waves per block (1024 threads)
constexpr int WSPAN = K / WAVES;      // 256 k per wave
constexpr int CH = 64;                // k per chunk
constexpr int NCH = WSPAN / CH;       // 4 chunks per wave

__device__ __forceinline__ unsigned int pk_bf16(float a, float b) {
    __hip_bfloat16 ha = __float2bfloat16(a), hb = __float2bfloat16(b);
    return (unsigned int)*reinterpret_cast<unsigned short*>(&ha) |
           ((unsigned int)*reinterpret_cast<unsigned short*>(&hb) << 16);
}

// ---- init: pack x into fragment-ordered bf16 (proven path).
// layout: [kblk(128)][half(2)][lane(64)][j(8)] shorts; lane L holds
// batch b = half*16 + (L&15), k = kblk*32 + (L>>4)*8 + j.
__global__ __launch_bounds__(256) void pack_x(
    const float* __restrict__ x, short* __restrict__ xfrag)
{
    int g = blockIdx.x * blockDim.x + threadIdx.x;   // 16384 threads
    int kblk = g >> 7, rem = g & 127;
    int half = rem >> 6, lane = rem & 63;
    int b = half * 16 + (lane & 15);
    int k = kblk * 32 + (lane >> 4) * 8;
    const float* src = x + (size_t)b * K + k;
    shortx8 v;
    #pragma unroll
    for (int j = 0; j < 8; ++j) {
        __hip_bfloat16 h = __float2bfloat16(src[j]);
        v[j] = *reinterpret_cast<short*>(&h);
    }
    *reinterpret_cast<shortx8*>(xfrag + (size_t)g * 8) = v;
}

// ---- main GEMM: 256 blocks (16 o-rows) x 1024 threads (16 waves, 4/SIMD).
// R12 dataflow: W coalesced -> reg dequant -> XOR-swizzled wave-private LDS ->
// swizzled ds_read_b128; x fragment register loads; per-block chunk rotation;
// 16-wave LDS reduce epilogue. Doubled TLP per SIMD vs R12 (probe-driven).
__global__ __launch_bounds__(1024, 4) void gemm_main(
    const float* __restrict__ W, const float* __restrict__ scales,
    const short* __restrict__ xfrag, const float* __restrict__ tscale,
    const float* __restrict__ bias, float* __restrict__ out)
{
    __shared__ __align__(16) char lds[WAVES * 2 * 2048];   // 64 KB

    const int t    = threadIdx.x;
    const int lane = t & 63;
    const int wave = t >> 6;
    const int o0   = blockIdx.x * 16;
    const int kw0  = wave * WSPAN;
    const int rot  = blockIdx.x & (NCH - 1);

    const float rt = 1.0f / tscale[0];

    // W staging per chunk: 16 rows x 64 k f32 = 4KB; per lane 4x float4.
    // flat = j*64+lane: row = flat>>4 (0..15), seg = flat&15 (16B units)
    floatx4 wr[2][4]; float sc[2][4];
    shortx8 xa[2][2], xb[2][2];

    auto issueW = [&](int c, int sl) {
        const int cm = (c + rot) & (NCH - 1);
        const int kc = kw0 + cm * CH;
        #pragma unroll
        for (int j = 0; j < 4; ++j) {
            int flat = j * 64 + lane, row = flat >> 4, seg = flat & 15;
            wr[sl][j] = *reinterpret_cast<const floatx4*>(
                W + (size_t)(o0 + row) * K + kc + seg * 4);
            sc[sl][j] = scales[(size_t)(o0 + row) * (K / 16) + (kc >> 4) + (seg >> 2)];
        }
        __builtin_amdgcn_sched_barrier(0);   // pin issue point
    };
    auto loadX = [&](int c, int sl) {
        const int cm = (c + rot) & (NCH - 1);
        const int kb0 = (kw0 + cm * CH) >> 5;
        #pragma unroll
        for (int b = 0; b < 2; ++b) {
            xa[sl][b] = *reinterpret_cast<const shortx8*>(
                xfrag + ((size_t)(kb0 + b) * 2 + 0) * 512 + lane * 8);
            xb[sl][b] = *reinterpret_cast<const shortx8*>(
                xfrag + ((size_t)(kb0 + b) * 2 + 1) * 512 + lane * 8);
        }
        __builtin_amdgcn_sched_barrier(0);
    };

    char* mybuf = lds + wave * 4096;
    auto stage = [&](int c, int sl) {
        char* buf = mybuf + sl * 2048;
        #pragma unroll
        for (int j = 0; j < 4; ++j) {
            int flat = j * 64 + lane, row = flat >> 4, seg = flat & 15;
            float rs = rt * __builtin_amdgcn_rcpf(sc[sl][j]);
            uintx2 pv = { pk_bf16(wr[sl][j][0] * rs, wr[sl][j][1] * rs),
                          pk_bf16(wr[sl][j][2] * rs, wr[sl][j][3] * rs) };
            int slot = seg >> 1, half = seg & 1;   // 8B granule within row
            *reinterpret_cast<uintx2*>(
                buf + row * 128 + ((slot ^ row) & 7) * 16 + half * 8) = pv;
        }
    };

    floatx4 acc0 = {0.f, 0.f, 0.f, 0.f};
    floatx4 acc1 = {0.f, 0.f, 0.f, 0.f};
    const int fr = lane & 15, kg = lane >> 4;

    issueW(0, 0);
    issueW(1, 1);
    loadX(0, 0);

    #pragma unroll
    for (int c = 0; c < NCH; ++c) {
        const int sl = c & 1;
        if (c + 1 < NCH) loadX(c + 1, sl ^ 1);   // x prefetch: other slot
        stage(c, sl);                             // consumes wr[sl]
        if (c + 2 < NCH) issueW(c + 2, sl);       // refill wr[sl] after use
        char* buf = mybuf + sl * 2048;
        #pragma unroll
        for (int b = 0; b < 2; ++b) {             // 2 k-steps of 32
            int slot = b * 4 + kg;
            shortx8 wf = *reinterpret_cast<const shortx8*>(
                buf + fr * 128 + ((slot ^ fr) & 7) * 16);
            acc0 = __builtin_amdgcn_mfma_f32_16x16x32_bf16(xa[sl][b], wf, acc0, 0, 0, 0);
            acc1 = __builtin_amdgcn_mfma_f32_16x16x32_bf16(xb[sl][b], wf, acc1, 0, 0, 0);
        }
    }

    // ---- in-block reduce across 16 waves (reuse LDS, 32 KB) ----
    __syncthreads();
    float* red = (float*)lds;               // [wave(16)][e(0..7)][lane(64)]
    #pragma unroll
    for (int r = 0; r < 4; ++r) {
        red[(wave * 8 + r) * 64 + lane]     = acc0[r];
        red[(wave * 8 + 4 + r) * 64 + lane] = acc1[r];
    }
    __syncthreads();

    // 512 outputs: t<512 -> (b = t>>4, oc = t&15); b = hi*16 + kgq*4 + r;
    // value at red[w][hi*4+r][kgq*16+oc]
    if (t < 512) {
        int b = t >> 4, oc = t & 15;
        int hi = b >> 4, kgq = (b >> 2) & 3, r = b & 3;
        int e = hi * 4 + r, ls = kgq * 16 + oc;
        float v = bias[o0 + oc];
        #pragma unroll
        for (int w = 0; w < WAVES; ++w)
            v += red[(w * 8 + e) * 64 + ls];
        out[(size_t)b * N + o0 + oc] = v;
    }
}

// ---- fallback (tiny ws): atomic split-K, x as f32
__global__ __launch_bounds__(256) void init_bias(
    const float* __restrict__ bias, float* __restrict__ out)
{
    int i = blockIdx.x * blockDim.x + threadIdx.x;
    if (i < M * N) out[i] = bias[i & (N - 1)];
}

__global__ __launch_bounds__(256) void gemm_atomic(
    const float* __restrict__ W, const float* __restrict__ scales,
    const float* __restrict__ xf32, const float* __restrict__ tscale,
    float* __restrict__ out)
{
    const int lane = threadIdx.x & 63;
    const int wave = threadIdx.x >> 6;
    const int o0 = blockIdx.x * 64 + wave * 16;
    const int k0 = blockIdx.y * 128;
    const int row = lane & 15, kg = lane >> 4;

    const float* wp  = W + (size_t)(o0 + row) * K + k0 + kg * 8;
    const float* sp  = scales + (size_t)(o0 + row) * (K / 16) + (k0 >> 4) + (kg >> 1);
    const float* xf0 = xf32 + (size_t)row * K + k0 + kg * 8;
    const float* xf1 = xf32 + (size_t)(row + 16) * K + k0 + kg * 8;
    const float rt = 1.0f / tscale[0];

    floatx4 acc0 = {0.f, 0.f, 0.f, 0.f};
    floatx4 acc1 = {0.f, 0.f, 0.f, 0.f};
    for (int i = 0; i < 4; ++i) {
        floatx4 w0 = *reinterpret_cast<const floatx4*>(wp + i * 32);
        floatx4 w1 = *reinterpret_cast<const floatx4*>(wp + i * 32 + 4);
        float s = sp[2 * i];
        shortx8 xav, xbv, wf;
        const float rs = rt / s;
        #pragma unroll
        for (int j = 0; j < 8; ++j) {
            float a = xf0[i * 32 + j], bb = xf1[i * 32 + j];
            float wv = (j < 4 ? w0[j] : w1[j - 4]) * rs;
            __hip_bfloat16 ha = __float2bfloat16(a);
            __hip_bfloat16 hb = __float2bfloat16(bb);
            __hip_bfloat16 hw = __float2bfloat16(wv);
            xav[j] = *reinterpret_cast<short*>(&ha);
            xbv[j] = *reinterpret_cast<short*>(&hb);
            wf[j]  = *reinterpret_cast<short*>(&hw);
        }
        acc0 = __builtin_amdgcn_mfma_f32_16x16x32_bf16(xav, wf, acc0, 0, 0, 0);
        acc1 = __builtin_amdgcn_mfma_f32_16x16x32_bf16(xbv, wf, acc1, 0, 0, 0);
    }
    float* op0 = out + (size_t)(kg * 4) * N + o0 + row;
    float* op1 = out + (size_t)(16 + kg * 4) * N + o0 + row;
    #pragma unroll
    for (int r = 0; r < 4; ++r) {
        atomicAdd(op0 + (size_t)r * N, acc0[r]);
        atomicAdd(op1 + (size_t)r * N, acc1[r]);
    }
}

extern "C" void kernel_launch(void* const* d_in, const int* in_sizes, int n_in,
                              void* d_out, int out_size, void* d_ws, size_t ws_size,
                              hipStream_t stream)
{
    const float* x      = (const float*)d_in[0];
    const float* W      = (const float*)d_in[1];
    const float* tscale = (const float*)d_in[2];
    const float* scales = (const float*)d_in[3];
    const float* bias   = (const float*)d_in[4];
    float* out = (float*)d_out;

    const size_t xfrag_bytes = (size_t)M * K * sizeof(short);   // 256 KiB

    if (ws_size >= xfrag_bytes) {
        short* xfrag = (short*)d_ws;
        pack_x<<<(M * K / 8 + 255) / 256, 256, 0, stream>>>(x, xfrag);
        gemm_main<<<N / 16, 1024, 0, stream>>>(W, scales, xfrag, tscale, bias, out);
    } else {
        init_bias<<<(M * N + 255) / 256, 256, 0, stream>>>(bias, out);
        dim3 grid(N / 64, K / 128);
        gemm_atomic<<<grid, 256, 0, stream>>>(W, scales, x, tscale, out);
    }
}